// Round 10
// baseline (85.846 us; speedup 1.0000x reference)
//
#include <hip/hip_runtime.h>
#include <math.h>

#define NB 32
#define GH 47
#define GW 47
#define NWIN (GH*GW)   // 2209
#define KSEL 16
#define RPITCH 17      // float4 per LDS row in k_encode (68 floats)
#define SEG 48         // 8-wide horizontal segments per row

// ---------------------------------------------------------------------------
// Kernel 1: per-window variance via separable f64 sums (unchanged, verified).
// ---------------------------------------------------------------------------
__global__ __launch_bounds__(256) void k_var(const float* __restrict__ x,
                                             float* __restrict__ var)
{
    __shared__ double hs [3][24][SEG];
    __shared__ double hs2[3][24][SEG];
    int gyp = blockIdx.x;     // 0..23
    int b   = blockIdx.y;
    int tid = threadIdx.x;
    int R0  = gyp * 16;

    for (int tau = tid; tau < 3*24*SEG; tau += 256) {
        int sg = tau % SEG;
        int t2 = tau / SEG;
        int rr = t2 % 24;
        int c  = t2 / 24;
        int row = R0 + rr;
        double s = 0.0, s2 = 0.0;
        if (row < 384) {
            const float* px = x + (((size_t)(b*3 + c)*384 + row)*384 + sg*8);
            #pragma unroll
            for (int q = 0; q < 2; ++q) {
                float4 v = *reinterpret_cast<const float4*>(px + q*4);
                double a0 = v.x, a1 = v.y, a2 = v.z, a3 = v.w;
                s  += a0 + a1 + a2 + a3;
                s2 = fma(a0,a0, fma(a1,a1, fma(a2,a2, fma(a3,a3, s2))));
            }
        }
        hs [c][rr][sg] = s;
        hs2[c][rr][sg] = s2;
    }
    __syncthreads();

    if (tid < 188) {
        int which = tid & 1;
        int rest  = tid >> 1;
        int gx = rest % 47, g = rest / 47;
        int gy = gyp*2 + g;
        if (gy < GH) {
            const double* base = which ? &hs2[0][0][0] : &hs[0][0][0];
            double S = 0.0;
            #pragma unroll
            for (int c = 0; c < 3; ++c)
                #pragma unroll
                for (int r = 0; r < 16; ++r) {
                    const double* rp = base + ((c*24) + (g*8 + r))*SEG + gx;
                    S += rp[0] + rp[1];
                }
            double P = __shfl_xor(S, 1, 64);
            if (which == 0) {
                var[(size_t)b*NWIN + gy*GW + gx] =
                    (float)((P - S*S/768.0) / 767.0);
            }
        }
    }
}

// ---------------------------------------------------------------------------
// Kernel 2: fused {all-wave LDS top-(krank+1)} + conv1+ReLU + decimated sums.
// 1024 thr / 16 waves. Selection: var staged to LDS once, then register-light
// iterative argmax using ALL 16 waves (u64 mono-key, tie -> smaller idx,
// matching jax.lax.top_k; verified packing from r2). No key[35] register
// array (r5's remat trap), no wave-0-only serial phase (r5), no dedicated
// 32-block kernel + graph gap (r6-r9: ~10-14 us serial latency).
// Conv core bit-identical to r7/r9: wave pair (2q,2q+1) owns ic-quad q;
// thread = (iy, xq) computes acc[4][8]; swizzled LDS tile; parity epilogue.
// ---------------------------------------------------------------------------
__global__ __launch_bounds__(1024, 1) void k_encode(const float* __restrict__ x,
    const float* __restrict__ w1, const float* __restrict__ b1,
    const float* __restrict__ var, float* __restrict__ sbuf)
{
    __shared__ float4 sin4[3*66*RPITCH];    // [c][row 0..65][17 f4], swizzled
    __shared__ float  lv[NWIN];             // per-batch variances
    __shared__ float4 w1t4[27*8];           // [ch*9+ky*3+kx][8 quads of 4 oc]
    __shared__ float4 b1t4[8];              // [quad][4 oc]
    __shared__ unsigned long long s_red[16];
    __shared__ float  s_part[16][2][4][3];  // [wave][iy-parity][i][kx]
    __shared__ float  s_c31[8][4][3];       // row-31 triple per ic-quad
    __shared__ int    s_hw[2];

    int p     = blockIdx.x;
    int bimg  = p >> 4;
    int krank = p & 15;
    int tid   = threadIdx.x;
    int wave  = tid >> 6;
    int lane  = tid & 63;

    float* sinf = (float*)sin4;
    float* w1tf = (float*)w1t4;
    float* b1tf = (float*)b1t4;

    // ---- Phase A: var -> LDS, weight preload, targeted pad zeroing ----
    {
        const float* vb = var + (size_t)bimg*NWIN;
        lv[tid] = vb[tid];
        lv[tid + 1024] = vb[tid + 1024];
        if (tid < NWIN - 2048) lv[tid + 2048] = vb[tid + 2048];
    }
    if (tid < 896) {
        if (tid < 864) w1tf[tid] = w1[(tid & 31)*27 + (tid >> 5)];
        else           b1tf[tid - 864] = b1[tid - 864];
    }
    if (tid < 243) {
        int c = tid / 81, j = tid - c*81;
        if (j < 17) {
            sin4[(c*66 + 0)*RPITCH + j] = make_float4(0.f, 0.f, 0.f, 0.f);
        } else {
            int r  = j - 16;                 // 1..64
            int sw = (r >> 1) & 7;
            sinf[((c*66 + r)*RPITCH + sw)*4] = 0.f;   // pcol 0 pad word
        }
    }
    __syncthreads();

    // ---- Phase B: iterative argmax, all 16 waves, register-light ----
    // key = (monotonic-f32-bits << 12) | (4095 - idx)
    for (int it = 0; ; ++it) {
        unsigned long long bk = 0ULL;
        {
            unsigned u0 = __float_as_uint(lv[tid]);
            unsigned m0 = u0 ^ ((unsigned)((int)u0 >> 31) | 0x80000000u);
            unsigned long long k0 =
                ((unsigned long long)m0 << 12) | (unsigned)(4095 - tid);
            unsigned u1 = __float_as_uint(lv[tid + 1024]);
            unsigned m1 = u1 ^ ((unsigned)((int)u1 >> 31) | 0x80000000u);
            unsigned long long k1 =
                ((unsigned long long)m1 << 12) | (unsigned)(4095 - (tid + 1024));
            bk = k0 > k1 ? k0 : k1;
            if (tid < NWIN - 2048) {
                unsigned u2 = __float_as_uint(lv[tid + 2048]);
                unsigned m2 = u2 ^ ((unsigned)((int)u2 >> 31) | 0x80000000u);
                unsigned long long k2 =
                    ((unsigned long long)m2 << 12) | (unsigned)(4095 - (tid + 2048));
                bk = k2 > bk ? k2 : bk;
            }
        }
        #pragma unroll
        for (int m = 1; m < 64; m <<= 1) {
            unsigned long long o = __shfl_xor(bk, m, 64);
            bk = o > bk ? o : bk;
        }
        if (lane == 0) s_red[wave] = bk;
        __syncthreads();
        if (wave == 0) {
            unsigned long long v = (lane < 16) ? s_red[lane] : 0ULL;
            #pragma unroll
            for (int m = 1; m < 16; m <<= 1) {
                unsigned long long o = __shfl_xor(v, m, 64);
                v = o > v ? o : v;
            }
            if (lane == 0) {
                int idx = 4095 - (int)(v & 0xFFFULL);
                if (it == krank) {
                    int h = (idx / 48) * 8; if (h > 320) h = 320;  // buggy /48
                    int w = (idx % 48) * 8; if (w > 320) w = 320;
                    s_hw[0] = h; s_hw[1] = w;
                } else {
                    lv[idx] = -INFINITY;
                }
            }
        }
        __syncthreads();
        if (it == krank) break;
    }

    int h0 = s_hw[0];
    int w0 = s_hw[1];

    // ---- Phase C: stage 3x64x64 patch (swizzled layout, data at y+1,x+1) --
    #pragma unroll
    for (int it = 0; it < 3; ++it) {
        int fi  = tid + it*1024;          // 0..3071
        int c   = fi >> 10;
        int rem = fi & 1023;
        int y   = rem >> 4;
        int x4  = rem & 15;
        float4 v = *reinterpret_cast<const float4*>(
            x + (((size_t)(bimg*3 + c)*384 + (h0 + y))*384 + w0 + x4*4));
        int r  = y + 1;
        int sw = (r >> 1) & 7;
        float vals[4] = {v.x, v.y, v.z, v.w};
        #pragma unroll
        for (int e = 0; e < 4; ++e) {
            int pcol = x4*4 + 1 + e;
            int k  = pcol >> 2, bb = pcol & 3;
            int ks = (k < 16) ? ((k & 8) | ((k & 7) ^ sw)) : 16;
            sinf[((c*66 + r)*RPITCH + ks)*4 + bb] = vals[e];
        }
    }
    __syncthreads();

    // ---- Phase D: conv + epilogue (identical to r7/r9) ----
    int sub  = wave & 1;
    int icq  = __builtin_amdgcn_readfirstlane(tid >> 7);  // ic-quad 0..7
    int iy   = sub*16 + (lane >> 2);   // conv1 output row 0..31
    int xq   = lane & 3;               // 8-col quarter

    float acc[4][8];
    #pragma unroll
    for (int i = 0; i < 4; ++i)
        #pragma unroll
        for (int u = 0; u < 8; ++u) acc[i][u] = 0.f;

    #pragma unroll 1
    for (int ch = 0; ch < 3; ++ch) {
        #pragma unroll 1
        for (int ky = 0; ky < 3; ++ky) {
            int widx = ch*9 + ky*3;
            float4 wv0 = w1t4[(widx + 0)*8 + icq];   // broadcast b128
            float4 wv1 = w1t4[(widx + 1)*8 + icq];
            float4 wv2 = w1t4[(widx + 2)*8 + icq];
            const float* pw0 = (const float*)&wv0;
            const float* pw1 = (const float*)&wv1;
            const float* pw2 = (const float*)&wv2;

            int r    = 2*iy + ky;                // padded input row
            int sw   = (r >> 1) & 7;
            int base = (ch*66 + r)*RPITCH;
            float s[17];                          // padded cols 16xq .. 16xq+16
            #pragma unroll
            for (int j = 0; j < 4; ++j) {
                int k = 4*xq + j;
                float4 v = sin4[base + ((k & 8) | ((k & 7) ^ sw))];
                s[4*j+0] = v.x; s[4*j+1] = v.y; s[4*j+2] = v.z; s[4*j+3] = v.w;
            }
            {
                int k  = 4*xq + 4;
                int ks = (k < 16) ? ((k & 8) | ((k & 7) ^ sw)) : 16;
                s[16] = sinf[(base + ks)*4];
            }
            #pragma unroll
            for (int i = 0; i < 4; ++i) {
                #pragma unroll
                for (int u = 0; u < 8; ++u)
                    acc[i][u] = fmaf(s[2*u], pw0[i],
                                 fmaf(s[2*u+1], pw1[i],
                                  fmaf(s[2*u+2], pw2[i], acc[i][u])));
            }
        }
    }

    // bias + ReLU + column-parity sums. global ix = 8*xq + u; parity = u&1.
    float4 bv = b1t4[icq];
    const float* pb = (const float*)&bv;
    float R[4][3];
    #pragma unroll
    for (int i = 0; i < 4; ++i) {
        float bias = pb[i];
        float c1 = 0.f, c2 = 0.f, v7 = 0.f;
        #pragma unroll
        for (int u = 0; u < 8; ++u) {
            float v = fmaxf(acc[i][u] + bias, 0.f);
            if (u & 1) c2 += v; else c1 += v;
            if (u == 7) v7 = v;
        }
        R[i][0] = c2 - ((xq == 3) ? v7 : 0.f);   // odd cols minus ix=31
        R[i][1] = c1;                            // even cols
        R[i][2] = c2;                            // odd cols
    }

    #pragma unroll
    for (int m = 1; m <= 2; m <<= 1)
        #pragma unroll
        for (int i = 0; i < 4; ++i)
            #pragma unroll
            for (int k = 0; k < 3; ++k)
                R[i][k] += __shfl_xor(R[i][k], m, 64);

    float c31[4][3];
    #pragma unroll
    for (int i = 0; i < 4; ++i)
        #pragma unroll
        for (int k = 0; k < 3; ++k)
            c31[i][k] = __shfl(R[i][k], 60, 64);

    #pragma unroll
    for (int m = 8; m < 64; m <<= 1)
        #pragma unroll
        for (int i = 0; i < 4; ++i)
            #pragma unroll
            for (int k = 0; k < 3; ++k)
                R[i][k] += __shfl_xor(R[i][k], m, 64);

    if (lane == 0) {
        #pragma unroll
        for (int i = 0; i < 4; ++i)
            #pragma unroll
            for (int k = 0; k < 3; ++k)
                s_part[wave][0][i][k] = R[i][k];
    } else if (lane == 4) {
        #pragma unroll
        for (int i = 0; i < 4; ++i)
            #pragma unroll
            for (int k = 0; k < 3; ++k)
                s_part[wave][1][i][k] = R[i][k];
    }
    if (sub == 1 && lane == 8) {
        #pragma unroll
        for (int i = 0; i < 4; ++i)
            #pragma unroll
            for (int k = 0; k < 3; ++k)
                s_c31[icq][i][k] = c31[i][k];
    }
    __syncthreads();

    if (tid < 288) {
        int ic = tid / 9, j = tid - ic*9;
        int ky = j / 3, kx = j - ky*3;
        int g = ic >> 2, i = ic & 3;
        float even = s_part[2*g][0][i][kx] + s_part[2*g+1][0][i][kx];
        float odd  = s_part[2*g][1][i][kx] + s_part[2*g+1][1][i][kx];
        float val = (ky == 1) ? even : odd;
        if (ky == 0) val = odd - s_c31[g][i][kx];
        sbuf[(size_t)p*288 + tid] = val;
    }
}

// ---------------------------------------------------------------------------
// Kernel 3: per batch: Ssum = sum_k S_k, then out = b2 + w2*Ssum / 4096
// ---------------------------------------------------------------------------
__global__ __launch_bounds__(256) void k_reduce(const float* __restrict__ sbuf,
    const float* __restrict__ w2, const float* __restrict__ b2,
    float* __restrict__ out)
{
    __shared__ float Ssum[288];
    __shared__ float s_part[256];
    int b = blockIdx.x, tid = threadIdx.x;

    for (int i = tid; i < 288; i += 256) {
        float s = 0.f;
        #pragma unroll
        for (int k = 0; k < KSEL; ++k)
            s += sbuf[(size_t)(b*KSEL + k)*288 + i];
        Ssum[i] = s;
    }
    __syncthreads();

    int oc = tid & 63, q = tid >> 6;
    const float4* w4 = reinterpret_cast<const float4*>(w2 + oc*288 + q*72);
    const float4* S4 = reinterpret_cast<const float4*>(Ssum + q*72);
    float a = 0.f;
    #pragma unroll
    for (int t = 0; t < 18; ++t) {
        float4 wv = w4[t];
        float4 sv = S4[t];
        a = fmaf(wv.x, sv.x, fmaf(wv.y, sv.y,
             fmaf(wv.z, sv.z, fmaf(wv.w, sv.w, a))));
    }
    s_part[tid] = a;
    __syncthreads();
    if (tid < 64) {
        float t = s_part[tid] + s_part[64 + tid] + s_part[128 + tid] + s_part[192 + tid];
        out[b*64 + tid] = b2[tid] + t * (1.0f/4096.0f);
    }
}

extern "C" void kernel_launch(void* const* d_in, const int* in_sizes, int n_in,
                              void* d_out, int out_size, void* d_ws, size_t ws_size,
                              hipStream_t stream)
{
    const float* x  = (const float*)d_in[0];
    const float* w1 = (const float*)d_in[1];
    const float* b1 = (const float*)d_in[2];
    const float* w2 = (const float*)d_in[3];
    const float* b2 = (const float*)d_in[4];
    float* out = (float*)d_out;

    char* ws = (char*)d_ws;
    float* var  = (float*)ws;                      // 32*2209*4 = 282,752 B
    float* sbuf = (float*)(ws + 283904);           // 512*288*4 = 589,824 B

    k_var   <<<dim3(24, NB), 256, 0, stream>>>(x, var);
    k_encode<<<NB*KSEL,     1024, 0, stream>>>(x, w1, b1, var, sbuf);
    k_reduce<<<NB,           256, 0, stream>>>(sbuf, w2, b2, out);
}

// Round 11
// 77.805 us; speedup vs baseline: 1.1034x; 1.1034x over previous
//
#include <hip/hip_runtime.h>
#include <math.h>

#define NB 32
#define GH 47
#define GW 47
#define NWIN (GH*GW)   // 2209
#define KSEL 16
#define RPITCH 17      // float4 per LDS row (68 floats)
#define SEG 48         // 8-wide horizontal segments per row

// ---------------------------------------------------------------------------
// Kernel 1: per-window variance via separable f64 sums (unchanged, verified).
// ---------------------------------------------------------------------------
__global__ __launch_bounds__(256) void k_var(const float* __restrict__ x,
                                             float* __restrict__ var)
{
    __shared__ double hs [3][24][SEG];
    __shared__ double hs2[3][24][SEG];
    int gyp = blockIdx.x;     // 0..23
    int b   = blockIdx.y;
    int tid = threadIdx.x;
    int R0  = gyp * 16;

    for (int tau = tid; tau < 3*24*SEG; tau += 256) {
        int sg = tau % SEG;
        int t2 = tau / SEG;
        int rr = t2 % 24;
        int c  = t2 / 24;
        int row = R0 + rr;
        double s = 0.0, s2 = 0.0;
        if (row < 384) {
            const float* px = x + (((size_t)(b*3 + c)*384 + row)*384 + sg*8);
            #pragma unroll
            for (int q = 0; q < 2; ++q) {
                float4 v = *reinterpret_cast<const float4*>(px + q*4);
                double a0 = v.x, a1 = v.y, a2 = v.z, a3 = v.w;
                s  += a0 + a1 + a2 + a3;
                s2 = fma(a0,a0, fma(a1,a1, fma(a2,a2, fma(a3,a3, s2))));
            }
        }
        hs [c][rr][sg] = s;
        hs2[c][rr][sg] = s2;
    }
    __syncthreads();

    if (tid < 188) {
        int which = tid & 1;
        int rest  = tid >> 1;
        int gx = rest % 47, g = rest / 47;
        int gy = gyp*2 + g;
        if (gy < GH) {
            const double* base = which ? &hs2[0][0][0] : &hs[0][0][0];
            double S = 0.0;
            #pragma unroll
            for (int c = 0; c < 3; ++c)
                #pragma unroll
                for (int r = 0; r < 16; ++r) {
                    const double* rp = base + ((c*24) + (g*8 + r))*SEG + gx;
                    S += rp[0] + rp[1];
                }
            double P = __shfl_xor(S, 1, 64);
            if (which == 0) {
                var[(size_t)b*NWIN + gy*GW + gx] =
                    (float)((P - S*S/768.0) / 767.0);
            }
        }
    }
}

// ---------------------------------------------------------------------------
// Kernel 2: per-batch top-16 (r2/r6 LDS iterative argmax, verified absmax 0).
// Tie -> smaller index (jax.lax.top_k). Buggy /48 decode + clamp.
// ---------------------------------------------------------------------------
__global__ __launch_bounds__(256) void k_topk(const float* __restrict__ var,
                                              int* __restrict__ coords)
{
    __shared__ float lv[NWIN];
    __shared__ float s_val[4];
    __shared__ int   s_idx[4];
    __shared__ int   chosen[KSEL];
    int b = blockIdx.x, tid = threadIdx.x;
    int lane = tid & 63, wavid = tid >> 6;

    for (int i = tid; i < NWIN; i += 256) lv[i] = var[(size_t)b*NWIN + i];
    __syncthreads();

    for (int k = 0; k < KSEL; ++k) {
        float bv = -INFINITY; int bi = NWIN;
        for (int i = tid; i < NWIN; i += 256) {
            float v = lv[i];
            if (v > bv) { bv = v; bi = i; }
        }
        #pragma unroll
        for (int m = 1; m < 64; m <<= 1) {
            float ov = __shfl_xor(bv, m, 64);
            int   oi = __shfl_xor(bi, m, 64);
            if (ov > bv || (ov == bv && oi < bi)) { bv = ov; bi = oi; }
        }
        if (lane == 0) { s_val[wavid] = bv; s_idx[wavid] = bi; }
        __syncthreads();
        if (tid == 0) {
            float cv = s_val[0]; int ci = s_idx[0];
            #pragma unroll
            for (int wv = 1; wv < 4; ++wv) {
                if (s_val[wv] > cv || (s_val[wv] == cv && s_idx[wv] < ci)) {
                    cv = s_val[wv]; ci = s_idx[wv];
                }
            }
            chosen[k] = ci;
            lv[ci] = -INFINITY;
        }
        __syncthreads();
    }

    if (tid < KSEL) {
        int idx = chosen[tid];
        int h = (idx / 48) * 8; if (h > 320) h = 320;
        int w = (idx % 48) * 8; if (w > 320) w = 320;
        coords[(b*KSEL + tid)*2 + 0] = h;
        coords[(b*KSEL + tid)*2 + 1] = w;
    }
}

// ---------------------------------------------------------------------------
// Kernel 3: conv1+ReLU + decimated partial sums, block = (patch, row-group).
// 1024 blocks x 512 thr: bid -> p = bid>>1, grp = bid&1 (output rows
// grp*16 .. grp*16+15). LDS tile = 3ch x 33 padded rows x 17 f4 (~27 KB)
// -> 4 independent blocks/CU (vs 2 monolithic before) for latency hiding.
// wave = ic-quad q (8 quads); lane = (iy' 0..15, xq 0..3); acc[4][8].
// Inner loop identical to the verified r7-r10 core; local row lr = r - 32g,
// swizzle sw = (lr>>1)&7 == ((32g+lr)>>1)&7 since 16g = 0 mod 8.
// Each block writes partial S[288] for (p,grp); k_reduce sums both groups.
// ---------------------------------------------------------------------------
__global__ __launch_bounds__(512, 2) void k_encode(const float* __restrict__ x,
    const float* __restrict__ w1, const float* __restrict__ b1,
    const int* __restrict__ coords, float* __restrict__ sbuf)
{
    __shared__ float4 sin4[3*33*RPITCH];    // [c][lr 0..32][17 f4], swizzled
    __shared__ float4 w1t4[27*8];           // [ch*9+ky*3+kx][8 quads of 4 oc]
    __shared__ float  s_part[8][2][4][3];   // [quad][iy-parity][i][kx]
    __shared__ float  s_c31[8][4][3];       // row-31 triple per quad (grp 1)

    int bid  = blockIdx.x;
    int p    = bid >> 1;
    int grp  = bid & 1;
    int bimg = p >> 4;
    int tid  = threadIdx.x;
    int h0 = coords[p*2 + 0];
    int w0 = coords[p*2 + 1];

    float* sinf = (float*)sin4;
    float* w1tf = (float*)w1t4;

    // weight preload (transposed), bias via direct read in epilogue
    for (int i = tid; i < 864; i += 512)
        w1tf[i] = w1[(i & 31)*27 + (i >> 5)];

    // targeted pad zeroing: pcol0 word of every row; full row lr=0 iff grp==0
    if (tid < 150) {
        if (tid < 99) {
            int c = tid / 33, lr = tid - c*33;
            int sw = (lr >> 1) & 7;
            sinf[((c*33 + lr)*RPITCH + sw)*4] = 0.f;
        } else if (grp == 0) {
            int j = tid - 99;                // 0..50
            int c = j / 17, f4i = j - c*17;
            sin4[(c*33 + 0)*RPITCH + f4i] = make_float4(0.f, 0.f, 0.f, 0.f);
        }
    }

    // stage rows: padded r = 32*grp + lr, image y = r-1; skip y<0 (zero row)
    #pragma unroll
    for (int it = 0; it < 4; ++it) {
        int fi = tid + it*512;               // 0..2047, tasks < 1584
        if (fi < 3*33*16) {
            int c   = fi / 528;
            int rem = fi - c*528;
            int lr  = rem >> 4;              // 0..32
            int x4  = rem & 15;
            int y   = 32*grp + lr - 1;
            if (y >= 0) {
                float4 v = *reinterpret_cast<const float4*>(
                    x + (((size_t)(bimg*3 + c)*384 + (h0 + y))*384 + w0 + x4*4));
                int sw = (lr >> 1) & 7;
                float vals[4] = {v.x, v.y, v.z, v.w};
                #pragma unroll
                for (int e = 0; e < 4; ++e) {
                    int pcol = x4*4 + 1 + e;
                    int k  = pcol >> 2, bb = pcol & 3;
                    int ks = (k < 16) ? ((k & 8) | ((k & 7) ^ sw)) : 16;
                    sinf[((c*33 + lr)*RPITCH + ks)*4 + bb] = vals[e];
                }
            }
        }
    }
    __syncthreads();

    int wave = tid >> 6;
    int lane = tid & 63;
    int icq  = __builtin_amdgcn_readfirstlane(wave);  // ic-quad 0..7
    int iyl  = lane >> 2;              // local output row 0..15
    int xq   = lane & 3;               // 8-col quarter

    float acc[4][8];
    #pragma unroll
    for (int i = 0; i < 4; ++i)
        #pragma unroll
        for (int u = 0; u < 8; ++u) acc[i][u] = 0.f;

    #pragma unroll 1
    for (int ch = 0; ch < 3; ++ch) {
        #pragma unroll 1
        for (int ky = 0; ky < 3; ++ky) {
            int widx = ch*9 + ky*3;
            float4 wv0 = w1t4[(widx + 0)*8 + icq];   // broadcast b128
            float4 wv1 = w1t4[(widx + 1)*8 + icq];
            float4 wv2 = w1t4[(widx + 2)*8 + icq];
            const float* pw0 = (const float*)&wv0;
            const float* pw1 = (const float*)&wv1;
            const float* pw2 = (const float*)&wv2;

            int lr   = 2*iyl + ky;               // local padded row 0..32
            int sw   = (lr >> 1) & 7;
            int base = (ch*33 + lr)*RPITCH;
            float s[17];                          // padded cols 16xq .. 16xq+16
            #pragma unroll
            for (int j = 0; j < 4; ++j) {
                int k = 4*xq + j;
                float4 v = sin4[base + ((k & 8) | ((k & 7) ^ sw))];
                s[4*j+0] = v.x; s[4*j+1] = v.y; s[4*j+2] = v.z; s[4*j+3] = v.w;
            }
            {
                int k  = 4*xq + 4;
                int ks = (k < 16) ? ((k & 8) | ((k & 7) ^ sw)) : 16;
                s[16] = sinf[(base + ks)*4];
            }
            #pragma unroll
            for (int i = 0; i < 4; ++i) {
                #pragma unroll
                for (int u = 0; u < 8; ++u)
                    acc[i][u] = fmaf(s[2*u], pw0[i],
                                 fmaf(s[2*u+1], pw1[i],
                                  fmaf(s[2*u+2], pw2[i], acc[i][u])));
            }
        }
    }

    // bias + ReLU + column-parity sums. global ix = 8*xq + u; parity = u&1.
    float R[4][3];
    #pragma unroll
    for (int i = 0; i < 4; ++i) {
        float bias = b1[icq*4 + i];
        float c1 = 0.f, c2 = 0.f, v7 = 0.f;
        #pragma unroll
        for (int u = 0; u < 8; ++u) {
            float v = fmaxf(acc[i][u] + bias, 0.f);
            if (u & 1) c2 += v; else c1 += v;
            if (u == 7) v7 = v;
        }
        R[i][0] = c2 - ((xq == 3) ? v7 : 0.f);   // odd cols minus ix=31
        R[i][1] = c1;                            // even cols
        R[i][2] = c2;                            // odd cols
    }

    // reduce over xq (lane bits 0,1)
    #pragma unroll
    for (int m = 1; m <= 2; m <<= 1)
        #pragma unroll
        for (int i = 0; i < 4; ++i)
            #pragma unroll
            for (int k = 0; k < 3; ++k)
                R[i][k] += __shfl_xor(R[i][k], m, 64);

    // local row-15 triple (= global row 31 when grp==1)
    float c31[4][3];
    #pragma unroll
    for (int i = 0; i < 4; ++i)
        #pragma unroll
        for (int k = 0; k < 3; ++k)
            c31[i][k] = __shfl(R[i][k], 60, 64);

    // reduce over iy bits 1..3 (lane bits 3,4,5), preserving parity (bit 2)
    #pragma unroll
    for (int m = 8; m < 64; m <<= 1)
        #pragma unroll
        for (int i = 0; i < 4; ++i)
            #pragma unroll
            for (int k = 0; k < 3; ++k)
                R[i][k] += __shfl_xor(R[i][k], m, 64);

    if (lane == 0) {                 // even local rows
        #pragma unroll
        for (int i = 0; i < 4; ++i)
            #pragma unroll
            for (int k = 0; k < 3; ++k)
                s_part[wave][0][i][k] = R[i][k];
    } else if (lane == 4) {          // odd local rows
        #pragma unroll
        for (int i = 0; i < 4; ++i)
            #pragma unroll
            for (int k = 0; k < 3; ++k)
                s_part[wave][1][i][k] = R[i][k];
    } else if (lane == 8) {
        #pragma unroll
        for (int i = 0; i < 4; ++i)
            #pragma unroll
            for (int k = 0; k < 3; ++k)
                s_c31[wave][i][k] = c31[i][k];
    }
    __syncthreads();

    // partial S for this row-group: ky=1 <- even rows; ky=2 <- odd rows;
    // ky=0 <- odd rows minus (grp==1 ? row 31 : nothing)
    if (tid < 288) {
        int ic = tid / 9, j = tid - ic*9;
        int ky = j / 3, kx = j - ky*3;
        int q = ic >> 2, i = ic & 3;
        float even = s_part[q][0][i][kx];
        float odd  = s_part[q][1][i][kx];
        float val = (ky == 1) ? even : odd;
        if (ky == 0 && grp == 1) val = odd - s_c31[q][i][kx];
        sbuf[(size_t)bid*288 + tid] = val;
    }
}

// ---------------------------------------------------------------------------
// Kernel 4: per batch: Ssum = sum over 32 chunks (16 patches x 2 groups),
// then out = b2 + w2*Ssum / 4096  (matvec commutes with the patch mean).
// ---------------------------------------------------------------------------
__global__ __launch_bounds__(256) void k_reduce(const float* __restrict__ sbuf,
    const float* __restrict__ w2, const float* __restrict__ b2,
    float* __restrict__ out)
{
    __shared__ float Ssum[288];
    __shared__ float s_part[256];
    int b = blockIdx.x, tid = threadIdx.x;

    for (int i = tid; i < 288; i += 256) {
        float s = 0.f;
        #pragma unroll
        for (int k = 0; k < 2*KSEL; ++k)
            s += sbuf[(size_t)(b*2*KSEL + k)*288 + i];
        Ssum[i] = s;
    }
    __syncthreads();

    int oc = tid & 63, q = tid >> 6;
    const float4* w4 = reinterpret_cast<const float4*>(w2 + oc*288 + q*72);
    const float4* S4 = reinterpret_cast<const float4*>(Ssum + q*72);
    float a = 0.f;
    #pragma unroll
    for (int t = 0; t < 18; ++t) {
        float4 wv = w4[t];
        float4 sv = S4[t];
        a = fmaf(wv.x, sv.x, fmaf(wv.y, sv.y,
             fmaf(wv.z, sv.z, fmaf(wv.w, sv.w, a))));
    }
    s_part[tid] = a;
    __syncthreads();
    if (tid < 64) {
        float t = s_part[tid] + s_part[64 + tid] + s_part[128 + tid] + s_part[192 + tid];
        out[b*64 + tid] = b2[tid] + t * (1.0f/4096.0f);
    }
}

extern "C" void kernel_launch(void* const* d_in, const int* in_sizes, int n_in,
                              void* d_out, int out_size, void* d_ws, size_t ws_size,
                              hipStream_t stream)
{
    const float* x  = (const float*)d_in[0];
    const float* w1 = (const float*)d_in[1];
    const float* b1 = (const float*)d_in[2];
    const float* w2 = (const float*)d_in[3];
    const float* b2 = (const float*)d_in[4];
    float* out = (float*)d_out;

    char* ws = (char*)d_ws;
    int*   coords = (int*)ws;                      // 4096 B
    float* var    = (float*)(ws + 4096);           // 32*2209*4 = 282,752 B
    float* sbuf   = (float*)(ws + 287744);         // 1024*288*4 = 1,179,648 B

    k_var   <<<dim3(24, NB),  256, 0, stream>>>(x, var);
    k_topk  <<<NB,            256, 0, stream>>>(var, coords);
    k_encode<<<NB*KSEL*2,     512, 0, stream>>>(x, w1, b1, coords, sbuf);
    k_reduce<<<NB,            256, 0, stream>>>(sbuf, w2, b2, out);
}